// Round 17
// baseline (37.427 us; speedup 1.0000x reference)
//
#include <hip/hip_runtime.h>
#include <math.h>

#define LQ 256
#define MEML 256
#define LK 512
#define BB 4
#define NH 8
#define DM 128

constexpr float INV2PI = 0.15915494309189535f;

// ---------------------------------------------------------------------------
// Projection (identical to R11/R12/R16), pre-scaled by paramR[h]/(2*pi):
//   qs[(i*32 + b*8 + h)*16 + d]      (row per (i,bh), 64B)
//   ksT[((d>>2)*512 + j)*128 + (b*8+h)*4 + (d&3)]
// ---------------------------------------------------------------------------
__global__ __launch_bounds__(128) void proj_kernel(
    const float* __restrict__ hh, const float* __restrict__ mems,
    const float* __restrict__ Wq, const float* __restrict__ Wk,
    const float* __restrict__ paramR,
    float* __restrict__ qs, float* __restrict__ ksT)
{
    __shared__ float x[8 * 128];
    const int blk = blockIdx.x;
    const int t = threadIdx.x;
    const bool isQ = (blk < 128);                 // 128 q-blocks, 256 k-blocks
    const int row0 = isQ ? blk * 8 : (blk - 128) * 8;
    const float* __restrict__ W = isQ ? Wq : Wk;

    for (int r = 0; r < 8; ++r) {
        const int row = row0 + r;
        const float* src = isQ ? (hh + row * DM)
                               : ((row < MEML * BB) ? (mems + row * DM)
                                                    : (hh + (row - MEML * BB) * DM));
        x[r * 128 + t] = src[t];
    }
    __syncthreads();

    float acc[8] = {0, 0, 0, 0, 0, 0, 0, 0};
    const float* wrow = W + t * DM;
    for (int k = 0; k < DM; k += 4) {
        const float4 w = *(const float4*)(wrow + k);
        #pragma unroll
        for (int r = 0; r < 8; ++r) {
            acc[r] += x[r * 128 + k + 0] * w.x + x[r * 128 + k + 1] * w.y
                    + x[r * 128 + k + 2] * w.z + x[r * 128 + k + 3] * w.w;
        }
    }
    const int h = t >> 4, d = t & 15;
    const float rs = paramR[h] * INV2PI;
    if (isQ) {
        #pragma unroll
        for (int r = 0; r < 8; ++r) {
            const int row = row0 + r;
            const int i = row >> 2, b = row & 3;
            qs[(i * 32 + b * 8 + h) * 16 + d] = acc[r] * rs;
        }
    } else {
        #pragma unroll
        for (int r = 0; r < 8; ++r) {
            const int row = row0 + r;
            const int j = row >> 2, b = row & 3;
            ksT[((d >> 2) * LK + j) * 128 + (b * 8 + h) * 4 + (d & 3)] = acc[r] * rs;
        }
    }
}

// ---------------------------------------------------------------------------
// Score: ALL operands register-resident before any arithmetic. Thread owns
// (j = by*8 + t>>5, bh = t&31); prologue = 4 k-loads + 8 q-loads (coalesced),
// then two pure-register sin-product chains (i0, i0+1), two stores, done.
// No LDS, no barriers, no mid-chain waits. 8192 blocks = ~32 generations/CU
// so prologue latency hides under other blocks' compute. lb(256,4): VGPR cap
// 128 so the compiler keeps everything live (R14 showed cap 64 -> VGPR=32 ->
// per-d operand re-reads serializing the chain).
// ---------------------------------------------------------------------------
__global__ __launch_bounds__(256, 4) void score_kernel(
    const float* __restrict__ qs, const float* __restrict__ ksT,
    float* __restrict__ out)
{
    const int t = threadIdx.x;
    const int bh = t & 31;
    const int js = t >> 5;                        // 0..7
    const int i0 = blockIdx.x * 2;                // 128 i-tiles
    const int j = blockIdx.y * 8 + js;            // 64 j-tiles of 8

    constexpr float i2 = INV2PI * INV2PI;
    constexpr float i4 = i2 * i2;
    constexpr float i8 = i4 * i4;
    constexpr float C16 = i8 * i8;                // (2pi)^-16
    constexpr float EPS = 2.0e-4f * INV2PI;       // 3.18e-5 rev; EPS^8 > FLT_MIN

    // ---- prologue: everything into registers ----
    float k[16];
    #pragma unroll
    for (int s = 0; s < 4; ++s) {
        const float4 v = *(const float4*)(ksT + (s * LK + j) * 128 + bh * 4);
        k[s * 4 + 0] = v.x; k[s * 4 + 1] = v.y;
        k[s * 4 + 2] = v.z; k[s * 4 + 3] = v.w;
    }
    float qa[16], qb[16];
    {
        const float* qpa = qs + ((i0 + 0) * 32 + bh) * 16;
        const float* qpb = qs + ((i0 + 1) * 32 + bh) * 16;
        #pragma unroll
        for (int s = 0; s < 4; ++s) {
            const float4 a = *(const float4*)(qpa + s * 4);
            const float4 b = *(const float4*)(qpb + s * 4);
            qa[s * 4 + 0] = a.x; qa[s * 4 + 1] = a.y;
            qa[s * 4 + 2] = a.z; qa[s * 4 + 3] = a.w;
            qb[s * 4 + 0] = b.x; qb[s * 4 + 1] = b.y;
            qb[s * 4 + 2] = b.z; qb[s * 4 + 3] = b.w;
        }
    }

    // ---- two pure-register chains, interleaved ----
    float pnA0 = 1.f, pdA0 = 1.f, pnA1 = 1.f, pdA1 = 1.f;
    float pnB0 = 1.f, pdB0 = 1.f, pnB1 = 1.f, pdB1 = 1.f;
    #pragma unroll
    for (int d = 0; d < 16; ++d) {
        const float uA = fmaxf(__builtin_fabsf(qa[d] - k[d]), EPS);
        const float uB = fmaxf(__builtin_fabsf(qb[d] - k[d]), EPS);
        const float sA = __builtin_amdgcn_sinf(uA);   // sin(2pi*u)
        const float sB = __builtin_amdgcn_sinf(uB);
        if (d < 8) { pnA0 *= sA; pdA0 *= uA; pnB0 *= sB; pdB0 *= uB; }
        else       { pnA1 *= sA; pdA1 *= uA; pnB1 *= sB; pdB1 *= uB; }
    }
    const float rA0 = pnA0 * __builtin_amdgcn_rcpf(pdA0);
    const float rA1 = pnA1 * __builtin_amdgcn_rcpf(pdA1);
    const float rB0 = pnB0 * __builtin_amdgcn_rcpf(pdB0);
    const float rB1 = pnB1 * __builtin_amdgcn_rcpf(pdB1);
    out[((i0 + 0) * LK + j) * 32 + bh] = __builtin_fabsf(rA0 * rA1) * C16;
    out[((i0 + 1) * LK + j) * 32 + bh] = __builtin_fabsf(rB0 * rB1) * C16;
}

extern "C" void kernel_launch(void* const* d_in, const int* in_sizes, int n_in,
                              void* d_out, int out_size, void* d_ws, size_t ws_size,
                              hipStream_t stream) {
    const float* hh     = (const float*)d_in[0];
    const float* mems   = (const float*)d_in[1];
    const float* Wq     = (const float*)d_in[2];
    const float* Wk     = (const float*)d_in[3];
    const float* paramR = (const float*)d_in[4];
    float* out = (float*)d_out;

    float* qs  = (float*)d_ws;                // 131072 floats
    float* ksT = qs + LQ * BB * DM;           // 262144 floats

    proj_kernel<<<384, 128, 0, stream>>>(hh, mems, Wq, Wk, paramR, qs, ksT);
    score_kernel<<<dim3(LQ / 2, LK / 8), 256, 0, stream>>>(qs, ksT, out);
}